// Round 13
// baseline (216.631 us; speedup 1.0000x reference)
//
#include <hip/hip_runtime.h>

#define NF 64        // feature width
#define BC 64        // edge chunks (12.5K edges each)
#define RANGE 16384  // nodes per hist range; packed uchar counters = 16 KB LDS
#define RWORDS (RANGE / 4)

typedef __attribute__((ext_vector_type(8))) short short8;    // 8 bf16 (4 VGPRs)
typedef __attribute__((ext_vector_type(4))) float floatx4;   // MFMA accumulator

// f32 -> bf16 round-to-nearest-even
__device__ __forceinline__ unsigned short f2bf(float f) {
  unsigned int u = __float_as_uint(f);
  return (unsigned short)((u + 0x7fffu + ((u >> 16) & 1u)) >> 16);
}

// ---------------------------------------------------------------------------
// Per-(range,chunk) histograms with PACKED 8-bit LDS counters (4/int, 16 KB:
// 10 blocks/CU cap; R=4 ranges vs r12's 7 -> 4/7 the redundant edge reads).
// Max count per (chunk,node) ~ Poisson(0.25) max < 10 << 255: no overflow.
// kind 0: dst -> Gin[b][node] (uchar) + rank[e] capture. kind 1: src -> Gout.
__global__ __launch_bounds__(256) void hist_kernel(
    const int* __restrict__ src, const int* __restrict__ dst,
    unsigned char* __restrict__ Gout, unsigned char* __restrict__ Gin,
    unsigned char* __restrict__ rank, int n, int nE, int R, int chunk) {
  __shared__ int cnt[RWORDS];
  const int rb = blockIdx.x % (R * BC);
  const int kind = blockIdx.x / (R * BC);
  const int r = rb / BC, b = rb % BC;
  const int r0 = r * RANGE;
  for (int i = threadIdx.x; i < RWORDS; i += 256) cnt[i] = 0;
  __syncthreads();
  const int lo = b * chunk, hi = min(lo + chunk, nE);
  const int* keys = kind ? src : dst;
  const int n4 = (hi > lo) ? ((hi - lo) >> 2) : 0;  // lo is 4-aligned
  const int4* keys4 = (const int4*)(keys + lo);
  if (kind == 0) {
    for (int i = threadIdx.x; i < n4; i += 256) {
      int4 v = keys4[i];
      int e0 = lo + 4 * i;
      unsigned int k, old, sh;
      k = (unsigned int)(v.x - r0);
      if (k < (unsigned int)RANGE) { sh = (k & 3) * 8; old = atomicAdd(&cnt[k >> 2], 1u << sh); rank[e0 + 0] = (unsigned char)(old >> sh); }
      k = (unsigned int)(v.y - r0);
      if (k < (unsigned int)RANGE) { sh = (k & 3) * 8; old = atomicAdd(&cnt[k >> 2], 1u << sh); rank[e0 + 1] = (unsigned char)(old >> sh); }
      k = (unsigned int)(v.z - r0);
      if (k < (unsigned int)RANGE) { sh = (k & 3) * 8; old = atomicAdd(&cnt[k >> 2], 1u << sh); rank[e0 + 2] = (unsigned char)(old >> sh); }
      k = (unsigned int)(v.w - r0);
      if (k < (unsigned int)RANGE) { sh = (k & 3) * 8; old = atomicAdd(&cnt[k >> 2], 1u << sh); rank[e0 + 3] = (unsigned char)(old >> sh); }
    }
    for (int e = lo + 4 * n4 + threadIdx.x; e < hi; e += 256) {
      unsigned int k = (unsigned int)(keys[e] - r0);
      if (k < (unsigned int)RANGE) {
        unsigned int sh = (k & 3) * 8;
        unsigned int old = atomicAdd(&cnt[k >> 2], 1u << sh);
        rank[e] = (unsigned char)(old >> sh);
      }
    }
    __syncthreads();
    unsigned int* Gw = (unsigned int*)(Gin + (size_t)b * n + r0);
    for (int i = threadIdx.x; i < RWORDS; i += 256)
      if (r0 + 4 * i < n) Gw[i] = (unsigned int)cnt[i];  // n%4==0: full words
  } else {
    for (int i = threadIdx.x; i < n4; i += 256) {
      int4 v = keys4[i];
      unsigned int k;
      k = (unsigned int)(v.x - r0);
      if (k < (unsigned int)RANGE) atomicAdd(&cnt[k >> 2], 1u << ((k & 3) * 8));
      k = (unsigned int)(v.y - r0);
      if (k < (unsigned int)RANGE) atomicAdd(&cnt[k >> 2], 1u << ((k & 3) * 8));
      k = (unsigned int)(v.z - r0);
      if (k < (unsigned int)RANGE) atomicAdd(&cnt[k >> 2], 1u << ((k & 3) * 8));
      k = (unsigned int)(v.w - r0);
      if (k < (unsigned int)RANGE) atomicAdd(&cnt[k >> 2], 1u << ((k & 3) * 8));
    }
    for (int e = lo + 4 * n4 + threadIdx.x; e < hi; e += 256) {
      unsigned int k = (unsigned int)(keys[e] - r0);
      if (k < (unsigned int)RANGE) atomicAdd(&cnt[k >> 2], 1u << ((k & 3) * 8));
    }
    __syncthreads();
    unsigned int* Gw = (unsigned int*)(Gout + (size_t)b * n + r0);
    for (int i = threadIdx.x; i < RWORDS; i += 256)
      if (r0 + 4 * i < n) Gw[i] = (unsigned int)cnt[i];
  }
}

// ---------------------------------------------------------------------------
// Fused colscan + scan1: per node, exclusive scan of Gin down the chunks
// (in place, uchar bases: deg_in max ~45 < 255) -> deg_in; sum Gout ->
// deg_out; then block-scan deg_in -> lscan + bsum.
__global__ __launch_bounds__(256) void colscan_scan1_kernel(
    unsigned char* __restrict__ Gin, const unsigned char* __restrict__ Gout,
    int* __restrict__ deg_in, int* __restrict__ deg_out,
    int* __restrict__ lscan, int* __restrict__ bsum, int n) {
  __shared__ int s[256];
  const int tid = threadIdx.x;
  const int i = blockIdx.x * 256 + tid;
  int di = 0;
  if (i < n) {
    int base = 0;
    #pragma unroll 8
    for (int b = 0; b < BC; ++b) {
      int c = Gin[(size_t)b * n + i];
      Gin[(size_t)b * n + i] = (unsigned char)base;
      base += c;
    }
    di = base;
    int dsum = 0;
    #pragma unroll 8
    for (int b = 0; b < BC; ++b) dsum += Gout[(size_t)b * n + i];
    deg_in[i] = di;
    deg_out[i] = dsum;
  }
  s[tid] = di;
  __syncthreads();
  #pragma unroll
  for (int off = 1; off < 256; off <<= 1) {
    int t2 = (tid >= off) ? s[tid - off] : 0;
    __syncthreads();
    s[tid] += t2;
    __syncthreads();
  }
  if (i < n) lscan[i] = s[tid] - di;
  if (tid == 255) bsum[blockIdx.x] = s[255];
}

// scan3: block b reduces bsum[0..b), finalizes row_start + deg^{-1/2}, and
// materializes base[b][i] = row_start[i] + Gin[b][i] (coalesced) so place
// needs ONE scattered read per edge.
__global__ __launch_bounds__(256) void scan3_kernel(
    const int* __restrict__ lscan, const int* __restrict__ bsum,
    const int* __restrict__ deg_out, const int* __restrict__ deg_in,
    const unsigned char* __restrict__ Gin, int* __restrict__ base,
    int* __restrict__ row_start, float* __restrict__ so, float* __restrict__ si,
    int n, int nE) {
  __shared__ int red[256];
  const int tid = threadIdx.x;
  const int b = blockIdx.x;
  red[tid] = (tid < b) ? bsum[tid] : 0;
  __syncthreads();
  #pragma unroll
  for (int s = 128; s > 0; s >>= 1) {
    if (tid < s) red[tid] += red[tid + s];
    __syncthreads();
  }
  const int off = red[0];
  const int i = b * 256 + tid;
  if (b == 0 && tid == 0) row_start[n] = nE;
  if (i < n) {
    int rs = lscan[i] + off;
    row_start[i] = rs;
    int dO = deg_out[i];
    int dI = deg_in[i];
    so[i] = dO > 0 ? rsqrtf((float)dO) : 0.f;
    si[i] = dI > 0 ? rsqrtf((float)dI) : 0.f;
    #pragma unroll 8
    for (int c = 0; c < BC; ++c)
      base[(size_t)c * n + i] = rs + (int)Gin[(size_t)c * n + i];
  }
}

// ---------------------------------------------------------------------------
// MFMA GEMM core: 64x64 tile, 4 waves, wave w owns rows [16w,16w+16).
// Verified layouts (m89/m91): A lane = A[m=lane&15][k=quad*8..+8); B from
// Bt=W^T rows; C/D col=lane&15, row=quad*4+reg. LDS stride 72 (2-way = free).
__device__ __forceinline__ void mfma_gemm_core(
    const unsigned short* __restrict__ Ab, const unsigned short* __restrict__ Wt,
    unsigned short* __restrict__ H, int row0, int n, int t) {
  const int w = t >> 6, lane = t & 63;
  const int quad = lane >> 4, l15 = lane & 15;
  const short8 a0 = *(const short8*)&Ab[(w * 16 + l15) * 72 + quad * 8];
  const short8 a1 = *(const short8*)&Ab[(w * 16 + l15) * 72 + 32 + quad * 8];
  #pragma unroll
  for (int cg = 0; cg < 4; ++cg) {
    const short8 b0 = *(const short8*)&Wt[(cg * 16 + l15) * 72 + quad * 8];
    const short8 b1 = *(const short8*)&Wt[(cg * 16 + l15) * 72 + 32 + quad * 8];
    floatx4 acc = {0.f, 0.f, 0.f, 0.f};
    acc = __builtin_amdgcn_mfma_f32_16x16x32_bf16(a0, b0, acc, 0, 0, 0);
    acc = __builtin_amdgcn_mfma_f32_16x16x32_bf16(a1, b1, acc, 0, 0, 0);
    #pragma unroll
    for (int reg = 0; reg < 4; ++reg) {
      int grow = row0 + w * 16 + quad * 4 + reg;
      if (grow < n) H[(size_t)grow * NF + cg * 16 + l15] = f2bf(acc[reg]);
    }
  }
}

// Stage W^T (f32 global -> bf16 LDS, [j][k] stride 72).
__device__ __forceinline__ void stage_wt(
    const float* __restrict__ W, unsigned short* __restrict__ Wt, int t) {
  #pragma unroll
  for (int i = 0; i < 16; ++i) {
    int idx = t + 256 * i;
    int k = idx >> 6, j = idx & 63;
    Wt[j * 72 + k] = f2bf(W[idx]);
  }
}

// Fused layer-1 MFMA GEMM + parallel atomic-free placement.
__global__ __launch_bounds__(256) void place_gemm1_kernel(
    const float* __restrict__ A, const float* __restrict__ so,
    const float* __restrict__ W, unsigned short* __restrict__ H, int n, int ggrid,
    const int* __restrict__ src, const int* __restrict__ dst,
    const unsigned char* __restrict__ rank, const int* __restrict__ base,
    unsigned short* __restrict__ sorted, int nE, int chunk) {
  __shared__ __align__(16) unsigned short Ab[64 * 72];
  __shared__ __align__(16) unsigned short Wt[64 * 72];
  const int t = threadIdx.x;
  if ((int)blockIdx.x >= ggrid) {
    int e = (blockIdx.x - ggrid) * 256 + t;
    if (e < nE) {
      int d = dst[e];
      int b = e / chunk;
      sorted[base[(size_t)b * n + d] + (int)rank[e]] = (unsigned short)src[e];
    }
    return;
  }
  stage_wt(W, Wt, t);
  const int row0 = blockIdx.x * 64;
  #pragma unroll
  for (int i = 0; i < 4; ++i) {
    int idx = t + 256 * i;
    int r = idx >> 4, c4 = idx & 15;
    int gr = row0 + r;
    float4 v = {0.f, 0.f, 0.f, 0.f};
    float s = 0.f;
    if (gr < n) {
      v = *(const float4*)&A[(size_t)gr * NF + c4 * 4];
      s = so[gr];
    }
    ushort4 o;
    o.x = f2bf(v.x * s); o.y = f2bf(v.y * s);
    o.z = f2bf(v.z * s); o.w = f2bf(v.w * s);
    *(ushort4*)&Ab[r * 72 + c4 * 4] = o;
  }
  __syncthreads();
  mfma_gemm_core(Ab, Wt, H, row0, n, t);
}

// Layer 2: h2 = bf16(t @ W2), bf16 input.
__global__ __launch_bounds__(256) void gemm2_kernel(
    const unsigned short* __restrict__ Tb, const float* __restrict__ W,
    unsigned short* __restrict__ H, int n) {
  __shared__ __align__(16) unsigned short Ab[64 * 72];
  __shared__ __align__(16) unsigned short Wt[64 * 72];
  const int t = threadIdx.x;
  stage_wt(W, Wt, t);
  const int row0 = blockIdx.x * 64;
  #pragma unroll
  for (int i = 0; i < 4; ++i) {
    int idx = t + 256 * i;
    int r = idx >> 4, c4 = idx & 15;
    int gr = row0 + r;
    ushort4 v = {0, 0, 0, 0};
    if (gr < n) v = *(const ushort4*)&Tb[(size_t)gr * NF + c4 * 4];
    *(ushort4*)&Ab[r * 72 + c4 * 4] = v;
  }
  __syncthreads();
  mfma_gemm_core(Ab, Wt, H, row0, n, t);
}

// ---------------------------------------------------------------------------
// Sliced gather/accumulate: only rows in this pass's src slice contribute
// (PASS 0: src < half ; PASS 1: src >= half). Masked lanes redirect to hot
// row 0 (one L2-resident line) so each pass's gathered working set is the
// 3.2 MB table half -> fits the 4 MiB per-XCD L2 (vs 6.4 MB unsliced = LLC).
template <int PASS>
__device__ __forceinline__ void gather_sliced(
    const unsigned short* __restrict__ H, const unsigned short* __restrict__ srcs,
    int beg, int end, int g, int c, int half, float* acc) {
  const float4* Hv = (const float4*)H;
  int e = beg;
  for (; e + 16 <= end; e += 16) {
    int ia = srcs[e + g];
    int ib = srcs[e + 8 + g];
    float ma = ((ia < half) == (PASS == 0)) ? 1.f : 0.f;
    float mb = ((ib < half) == (PASS == 0)) ? 1.f : 0.f;
    int iae = (ma != 0.f) ? ia : 0;
    int ibe = (mb != 0.f) ? ib : 0;
    float4 va = Hv[(size_t)iae * 8 + c];
    float4 vb = Hv[(size_t)ibe * 8 + c];
    const unsigned int* pa = (const unsigned int*)&va;
    const unsigned int* pb = (const unsigned int*)&vb;
    #pragma unroll
    for (int k = 0; k < 4; ++k) {
      acc[2 * k]     = fmaf(ma, __uint_as_float(pa[k] << 16), acc[2 * k]);
      acc[2 * k]     = fmaf(mb, __uint_as_float(pb[k] << 16), acc[2 * k]);
      acc[2 * k + 1] = fmaf(ma, __uint_as_float(pa[k] & 0xffff0000u), acc[2 * k + 1]);
      acc[2 * k + 1] = fmaf(mb, __uint_as_float(pb[k] & 0xffff0000u), acc[2 * k + 1]);
    }
  }
  if (e + 8 <= end) {
    int ia = srcs[e + g];
    float ma = ((ia < half) == (PASS == 0)) ? 1.f : 0.f;
    int iae = (ma != 0.f) ? ia : 0;
    float4 va = Hv[(size_t)iae * 8 + c];
    const unsigned int* pa = (const unsigned int*)&va;
    #pragma unroll
    for (int k = 0; k < 4; ++k) {
      acc[2 * k]     = fmaf(ma, __uint_as_float(pa[k] << 16), acc[2 * k]);
      acc[2 * k + 1] = fmaf(ma, __uint_as_float(pa[k] & 0xffff0000u), acc[2 * k + 1]);
    }
    e += 8;
  }
  if (e < end) {
    int idx = (e + g < end) ? (e + g) : (end - 1);
    int ia = srcs[idx];
    float m = ((e + g < end) && ((ia < half) == (PASS == 0))) ? 1.f : 0.f;
    int iae = (m != 0.f) ? ia : 0;
    float4 va = Hv[(size_t)iae * 8 + c];
    const unsigned int* pa = (const unsigned int*)&va;
    #pragma unroll
    for (int k = 0; k < 4; ++k) {
      acc[2 * k]     = fmaf(m, __uint_as_float(pa[k] << 16), acc[2 * k]);
      acc[2 * k + 1] = fmaf(m, __uint_as_float(pa[k] & 0xffff0000u), acc[2 * k + 1]);
    }
  }
  #pragma unroll
  for (int d = 8; d <= 32; d <<= 1) {
    #pragma unroll
    for (int k = 0; k < 8; ++k) acc[k] += __shfl_xor(acc[k], d);
  }
}

// Layer-1 aggregation. PASS 0: slice-0 partial -> P (f32).
// PASS 1: slice-1 + P, epilogue relu(sum*si+b1)*so -> tb (bf16).
template <int PASS>
__global__ __launch_bounds__(256) void agg1_kernel(
    const unsigned short* __restrict__ H1, const int* __restrict__ row_start,
    const unsigned short* __restrict__ srcs, const float* __restrict__ si,
    const float* __restrict__ so, const float* __restrict__ b1,
    float* __restrict__ P, unsigned short* __restrict__ T, int n, int half) {
  int node = blockIdx.x * 4 + (threadIdx.x >> 6);
  if (node >= n) return;
  const int lane = threadIdx.x & 63;
  const int g = lane >> 3;
  const int c = lane & 7;
  float acc[8] = {0, 0, 0, 0, 0, 0, 0, 0};
  gather_sliced<PASS>(H1, srcs, row_start[node], row_start[node + 1], g, c, half, acc);
  if (g != 0) return;
  if (PASS == 0) {
    *(float4*)&P[(size_t)node * NF + c * 8]     = make_float4(acc[0], acc[1], acc[2], acc[3]);
    *(float4*)&P[(size_t)node * NF + c * 8 + 4] = make_float4(acc[4], acc[5], acc[6], acc[7]);
  } else {
    const float4 p0 = *(const float4*)&P[(size_t)node * NF + c * 8];
    const float4 p1 = *(const float4*)&P[(size_t)node * NF + c * 8 + 4];
    const float pp[8] = {p0.x, p0.y, p0.z, p0.w, p1.x, p1.y, p1.z, p1.w};
    const float sin = si[node];
    const float son = so[node];
    ushort4 o0, o1;
    float v;
    v = fmaxf(fmaf(acc[0] + pp[0], sin, b1[c * 8 + 0]), 0.f) * son; o0.x = f2bf(v);
    v = fmaxf(fmaf(acc[1] + pp[1], sin, b1[c * 8 + 1]), 0.f) * son; o0.y = f2bf(v);
    v = fmaxf(fmaf(acc[2] + pp[2], sin, b1[c * 8 + 2]), 0.f) * son; o0.z = f2bf(v);
    v = fmaxf(fmaf(acc[3] + pp[3], sin, b1[c * 8 + 3]), 0.f) * son; o0.w = f2bf(v);
    v = fmaxf(fmaf(acc[4] + pp[4], sin, b1[c * 8 + 4]), 0.f) * son; o1.x = f2bf(v);
    v = fmaxf(fmaf(acc[5] + pp[5], sin, b1[c * 8 + 5]), 0.f) * son; o1.y = f2bf(v);
    v = fmaxf(fmaf(acc[6] + pp[6], sin, b1[c * 8 + 6]), 0.f) * son; o1.z = f2bf(v);
    v = fmaxf(fmaf(acc[7] + pp[7], sin, b1[c * 8 + 7]), 0.f) * son; o1.w = f2bf(v);
    *(ushort4*)&T[(size_t)node * NF + c * 8]     = o0;
    *(ushort4*)&T[(size_t)node * NF + c * 8 + 4] = o1;
  }
}

// Layer-2 aggregation. PASS 0: slice-0 partial -> P. PASS 1: + epilogue -> out.
template <int PASS>
__global__ __launch_bounds__(256) void agg2_kernel(
    const unsigned short* __restrict__ H2, const int* __restrict__ row_start,
    const unsigned short* __restrict__ srcs, const float* __restrict__ si,
    const float* __restrict__ b2, float* __restrict__ P,
    float* __restrict__ out, int n, int half) {
  int node = blockIdx.x * 4 + (threadIdx.x >> 6);
  if (node >= n) return;
  const int lane = threadIdx.x & 63;
  const int g = lane >> 3;
  const int c = lane & 7;
  float acc[8] = {0, 0, 0, 0, 0, 0, 0, 0};
  gather_sliced<PASS>(H2, srcs, row_start[node], row_start[node + 1], g, c, half, acc);
  if (g != 0) return;
  if (PASS == 0) {
    *(float4*)&P[(size_t)node * NF + c * 8]     = make_float4(acc[0], acc[1], acc[2], acc[3]);
    *(float4*)&P[(size_t)node * NF + c * 8 + 4] = make_float4(acc[4], acc[5], acc[6], acc[7]);
  } else {
    const float4 p0 = *(const float4*)&P[(size_t)node * NF + c * 8];
    const float4 p1 = *(const float4*)&P[(size_t)node * NF + c * 8 + 4];
    const float sin = si[node];
    const float4 b4a = *(const float4*)&b2[c * 8];
    const float4 b4b = *(const float4*)&b2[c * 8 + 4];
    float4 r0, r1;
    r0.x = fmaf(acc[0] + p0.x, sin, b4a.x);
    r0.y = fmaf(acc[1] + p0.y, sin, b4a.y);
    r0.z = fmaf(acc[2] + p0.z, sin, b4a.z);
    r0.w = fmaf(acc[3] + p0.w, sin, b4a.w);
    r1.x = fmaf(acc[4] + p1.x, sin, b4b.x);
    r1.y = fmaf(acc[5] + p1.y, sin, b4b.y);
    r1.z = fmaf(acc[6] + p1.z, sin, b4b.z);
    r1.w = fmaf(acc[7] + p1.w, sin, b4b.w);
    *(float4*)&out[(size_t)node * NF + c * 8]     = r0;
    *(float4*)&out[(size_t)node * NF + c * 8 + 4] = r1;
  }
}

// ---------------------------------------------------------------------------
extern "C" void kernel_launch(void* const* d_in, const int* in_sizes, int n_in,
                              void* d_out, int out_size, void* d_ws, size_t ws_size,
                              hipStream_t stream) {
  const float* x  = (const float*)d_in[0];
  const float* W1 = (const float*)d_in[1];
  const float* b1 = (const float*)d_in[2];
  const float* W2 = (const float*)d_in[3];
  const float* b2 = (const float*)d_in[4];
  const int* src  = (const int*)d_in[5];
  const int* dst  = (const int*)d_in[6];
  float* out = (float*)d_out;

  const int N = in_sizes[0] / NF;   // 50000 (< 65536 for ushort ids; %4==0)
  const int E = in_sizes[5];        // 800000
  const int NB = (N + 255) / 256;
  const int R  = (N + RANGE - 1) / RANGE;        // 4
  const int CH = (((E + BC - 1) / BC) + 3) & ~3; // 12500, 4-aligned
  const int HALF = N / 2;

  // Workspace (~36 MB of the 256 MiB ws). base (12.8 MB int) aliases
  // [tb, G_out, P-head]: all dead during scan3->place; tb/P written only
  // after place completes.
  char* ws = (char*)d_ws;
  size_t p = 0;
  auto alloc = [&](size_t bytes) -> void* {
    void* r = ws + p;
    p = (p + bytes + 255) & ~(size_t)255;
    return r;
  };
  int*   deg_out_i  = (int*)  alloc((size_t)N * 4);
  int*   deg_in_i   = (int*)  alloc((size_t)N * 4);
  float* so         = (float*)alloc((size_t)N * 4);
  float* si         = (float*)alloc((size_t)N * 4);
  int*   row_start  = (int*)  alloc((size_t)(N + 1) * 4);
  int*   bsum       = (int*)  alloc((size_t)NB * 4);
  int*   lscan      = (int*)  alloc((size_t)N * 4);
  unsigned short* sorted_u16 = (unsigned short*)alloc((size_t)E * 2);
  unsigned char*  rank  = (unsigned char*)alloc((size_t)E);             // 0.8 MB
  unsigned short* h1    = (unsigned short*)alloc((size_t)N * NF * 2);   // 6.4 MB
  unsigned char*  G_in  = (unsigned char*)alloc((size_t)BC * N);        // 3.2 MB
  unsigned short* tb    = (unsigned short*)alloc((size_t)N * NF * 2);   // 6.4 MB
  unsigned char*  G_out = (unsigned char*)alloc((size_t)BC * N);        // 3.2 MB
  float*          P     = (float*)alloc((size_t)N * NF * 4);            // 12.8 MB
  int* base = (int*)tb;        // 12.8 MB alias over [tb, G_out, P-head]
  unsigned short* h2 = h1;     // h1 dead after agg1 passes; gemm2 runs after

  // 1. packed-uchar histograms for both endpoints (+ rank capture)
  hist_kernel<<<2 * R * BC, 256, 0, stream>>>(src, dst, G_out, G_in, rank,
                                              N, E, R, CH);

  // 2. fused column-scan (per-chunk bases + degrees) + block scan
  colscan_scan1_kernel<<<NB, 256, 0, stream>>>(G_in, G_out, deg_in_i, deg_out_i,
                                               lscan, bsum, N);

  // 3. row_start + so/si + base matrix
  scan3_kernel<<<NB, 256, 0, stream>>>(lscan, bsum, deg_out_i, deg_in_i,
                                       G_in, base, row_start, so, si, N, E);

  const int ggrid = (N + 63) / 64;
  const int pgrid = (E + 255) / 256;
  const int agrid = (N + 3) / 4;

  // 4. fused: layer-1 MFMA GEMM (h1) + parallel atomic-free placement
  place_gemm1_kernel<<<ggrid + pgrid, 256, 0, stream>>>(
      x, so, W1, h1, N, ggrid, src, dst, rank, base, sorted_u16, E, CH);

  // 5-6. layer-1 aggregation, two L2-resident src slices -> tb (bf16)
  agg1_kernel<0><<<agrid, 256, 0, stream>>>(h1, row_start, sorted_u16, si, so, b1, P, tb, N, HALF);
  agg1_kernel<1><<<agrid, 256, 0, stream>>>(h1, row_start, sorted_u16, si, so, b1, P, tb, N, HALF);

  // 7. h2 = bf16(t @ W2)   [MFMA]
  gemm2_kernel<<<ggrid, 256, 0, stream>>>(tb, W2, h2, N);

  // 8-9. layer-2 aggregation, two slices -> out (f32)
  agg2_kernel<0><<<agrid, 256, 0, stream>>>(h2, row_start, sorted_u16, si, b2, P, out, N, HALF);
  agg2_kernel<1><<<agrid, 256, 0, stream>>>(h2, row_start, sorted_u16, si, b2, P, out, N, HALF);
}

// Round 14
// 183.223 us; speedup vs baseline: 1.1823x; 1.1823x over previous
//
#include <hip/hip_runtime.h>

#define NF 64        // feature width
#define BC 64        // edge chunks (12.5K edges each)
#define RANGE 16384  // nodes per hist range; packed uchar counters = 16 KB LDS
#define RWORDS (RANGE / 4)

typedef __attribute__((ext_vector_type(8))) short short8;    // 8 bf16 (4 VGPRs)
typedef __attribute__((ext_vector_type(4))) float floatx4;   // MFMA accumulator

// f32 -> bf16 round-to-nearest-even
__device__ __forceinline__ unsigned short f2bf(float f) {
  unsigned int u = __float_as_uint(f);
  return (unsigned short)((u + 0x7fffu + ((u >> 16) & 1u)) >> 16);
}

// ---------------------------------------------------------------------------
// Per-(range,chunk) histograms with packed 8-bit LDS counters (4/int, 16 KB).
// Counts per (chunk,node) are tiny (Poisson(0.25), max << 255): no overflow.
// kind 0: dst -> Gin[b][node] (uchar) + rank[e] capture (arrival index within
// the (chunk,node) bucket — any bijection is valid for a segment-sum).
// kind 1: src -> Gout[b][node].
__global__ __launch_bounds__(256) void hist_kernel(
    const int* __restrict__ src, const int* __restrict__ dst,
    unsigned char* __restrict__ Gout, unsigned char* __restrict__ Gin,
    unsigned char* __restrict__ rank, int n, int nE, int R, int chunk) {
  __shared__ int cnt[RWORDS];
  const int rb = blockIdx.x % (R * BC);
  const int kind = blockIdx.x / (R * BC);
  const int r = rb / BC, b = rb % BC;
  const int r0 = r * RANGE;
  for (int i = threadIdx.x; i < RWORDS; i += 256) cnt[i] = 0;
  __syncthreads();
  const int lo = b * chunk, hi = min(lo + chunk, nE);
  const int* keys = kind ? src : dst;
  const int n4 = (hi > lo) ? ((hi - lo) >> 2) : 0;  // lo is 4-aligned
  const int4* keys4 = (const int4*)(keys + lo);
  if (kind == 0) {
    for (int i = threadIdx.x; i < n4; i += 256) {
      int4 v = keys4[i];
      int e0 = lo + 4 * i;
      unsigned int k, old, sh;
      k = (unsigned int)(v.x - r0);
      if (k < (unsigned int)RANGE) { sh = (k & 3) * 8; old = atomicAdd(&cnt[k >> 2], 1u << sh); rank[e0 + 0] = (unsigned char)(old >> sh); }
      k = (unsigned int)(v.y - r0);
      if (k < (unsigned int)RANGE) { sh = (k & 3) * 8; old = atomicAdd(&cnt[k >> 2], 1u << sh); rank[e0 + 1] = (unsigned char)(old >> sh); }
      k = (unsigned int)(v.z - r0);
      if (k < (unsigned int)RANGE) { sh = (k & 3) * 8; old = atomicAdd(&cnt[k >> 2], 1u << sh); rank[e0 + 2] = (unsigned char)(old >> sh); }
      k = (unsigned int)(v.w - r0);
      if (k < (unsigned int)RANGE) { sh = (k & 3) * 8; old = atomicAdd(&cnt[k >> 2], 1u << sh); rank[e0 + 3] = (unsigned char)(old >> sh); }
    }
    for (int e = lo + 4 * n4 + threadIdx.x; e < hi; e += 256) {
      unsigned int k = (unsigned int)(keys[e] - r0);
      if (k < (unsigned int)RANGE) {
        unsigned int sh = (k & 3) * 8;
        unsigned int old = atomicAdd(&cnt[k >> 2], 1u << sh);
        rank[e] = (unsigned char)(old >> sh);
      }
    }
    __syncthreads();
    unsigned int* Gw = (unsigned int*)(Gin + (size_t)b * n + r0);
    for (int i = threadIdx.x; i < RWORDS; i += 256)
      if (r0 + 4 * i < n) Gw[i] = (unsigned int)cnt[i];  // n%4==0: full words
  } else {
    for (int i = threadIdx.x; i < n4; i += 256) {
      int4 v = keys4[i];
      unsigned int k;
      k = (unsigned int)(v.x - r0);
      if (k < (unsigned int)RANGE) atomicAdd(&cnt[k >> 2], 1u << ((k & 3) * 8));
      k = (unsigned int)(v.y - r0);
      if (k < (unsigned int)RANGE) atomicAdd(&cnt[k >> 2], 1u << ((k & 3) * 8));
      k = (unsigned int)(v.z - r0);
      if (k < (unsigned int)RANGE) atomicAdd(&cnt[k >> 2], 1u << ((k & 3) * 8));
      k = (unsigned int)(v.w - r0);
      if (k < (unsigned int)RANGE) atomicAdd(&cnt[k >> 2], 1u << ((k & 3) * 8));
    }
    for (int e = lo + 4 * n4 + threadIdx.x; e < hi; e += 256) {
      unsigned int k = (unsigned int)(keys[e] - r0);
      if (k < (unsigned int)RANGE) atomicAdd(&cnt[k >> 2], 1u << ((k & 3) * 8));
    }
    __syncthreads();
    unsigned int* Gw = (unsigned int*)(Gout + (size_t)b * n + r0);
    for (int i = threadIdx.x; i < RWORDS; i += 256)
      if (r0 + 4 * i < n) Gw[i] = (unsigned int)cnt[i];
  }
}

// ---------------------------------------------------------------------------
// Fused colscan + scan1 (+ so/si: degrees are known here — r12 computed them
// in scan3, one kernel later than necessary). Per node: exclusive scan of
// Gin down the chunks (in place, uchar bases; deg_in max ~45 < 255) ->
// deg_in; sum Gout -> deg_out; si/so = deg^{-1/2}; block-scan -> lscan+bsum.
__global__ __launch_bounds__(256) void colscan_scan1_kernel(
    unsigned char* __restrict__ Gin, const unsigned char* __restrict__ Gout,
    float* __restrict__ so, float* __restrict__ si,
    int* __restrict__ lscan, int* __restrict__ bsum, int n) {
  __shared__ int s[256];
  const int tid = threadIdx.x;
  const int i = blockIdx.x * 256 + tid;
  int di = 0;
  if (i < n) {
    int base = 0;
    #pragma unroll 8
    for (int b = 0; b < BC; ++b) {
      int c = Gin[(size_t)b * n + i];
      Gin[(size_t)b * n + i] = (unsigned char)base;
      base += c;
    }
    di = base;
    int dsum = 0;
    #pragma unroll 8
    for (int b = 0; b < BC; ++b) dsum += Gout[(size_t)b * n + i];
    si[i] = di > 0 ? rsqrtf((float)di) : 0.f;
    so[i] = dsum > 0 ? rsqrtf((float)dsum) : 0.f;
  }
  s[tid] = di;
  __syncthreads();
  #pragma unroll
  for (int off = 1; off < 256; off <<= 1) {
    int t2 = (tid >= off) ? s[tid - off] : 0;
    __syncthreads();
    s[tid] += t2;
    __syncthreads();
  }
  if (i < n) lscan[i] = s[tid] - di;
  if (tid == 255) bsum[blockIdx.x] = s[255];
}

// scan3 (slim): block b reduces bsum[0..b), finalizes row_start only.
__global__ __launch_bounds__(256) void scan3_kernel(
    const int* __restrict__ lscan, const int* __restrict__ bsum,
    int* __restrict__ row_start, int n, int nE) {
  __shared__ int red[256];
  const int tid = threadIdx.x;
  const int b = blockIdx.x;
  red[tid] = (tid < b) ? bsum[tid] : 0;
  __syncthreads();
  #pragma unroll
  for (int s = 128; s > 0; s >>= 1) {
    if (tid < s) red[tid] += red[tid + s];
    __syncthreads();
  }
  const int off = red[0];
  const int i = b * 256 + tid;
  if (b == 0 && tid == 0) row_start[n] = nE;
  if (i < n) row_start[i] = lscan[i] + off;
}

// basefill: base[c][i] = row_start[i] + Gin[c][i], one coalesced read+write
// per block over a BC*NB grid (r12 did this as 64 serial iterations inside
// scan3's 196-block grid -> 1 block/CU latency-bound, ~13us; this is ~4us).
__global__ __launch_bounds__(256) void basefill_kernel(
    const int* __restrict__ row_start, const unsigned char* __restrict__ Gin,
    int* __restrict__ base, int n, int nb) {
  const int c = blockIdx.x / nb;
  const int i = (blockIdx.x % nb) * 256 + threadIdx.x;
  if (i < n) base[(size_t)c * n + i] = row_start[i] + (int)Gin[(size_t)c * n + i];
}

// ---------------------------------------------------------------------------
// MFMA GEMM core: 64x64 tile, 4 waves, wave w owns rows [16w,16w+16).
// Verified layouts (m89/m91): A lane = A[m=lane&15][k=quad*8..+8); B from
// Bt=W^T rows; C/D col=lane&15, row=quad*4+reg. LDS stride 72 (2-way = free).
__device__ __forceinline__ void mfma_gemm_core(
    const unsigned short* __restrict__ Ab, const unsigned short* __restrict__ Wt,
    unsigned short* __restrict__ H, int row0, int n, int t) {
  const int w = t >> 6, lane = t & 63;
  const int quad = lane >> 4, l15 = lane & 15;
  const short8 a0 = *(const short8*)&Ab[(w * 16 + l15) * 72 + quad * 8];
  const short8 a1 = *(const short8*)&Ab[(w * 16 + l15) * 72 + 32 + quad * 8];
  #pragma unroll
  for (int cg = 0; cg < 4; ++cg) {
    const short8 b0 = *(const short8*)&Wt[(cg * 16 + l15) * 72 + quad * 8];
    const short8 b1 = *(const short8*)&Wt[(cg * 16 + l15) * 72 + 32 + quad * 8];
    floatx4 acc = {0.f, 0.f, 0.f, 0.f};
    acc = __builtin_amdgcn_mfma_f32_16x16x32_bf16(a0, b0, acc, 0, 0, 0);
    acc = __builtin_amdgcn_mfma_f32_16x16x32_bf16(a1, b1, acc, 0, 0, 0);
    #pragma unroll
    for (int reg = 0; reg < 4; ++reg) {
      int grow = row0 + w * 16 + quad * 4 + reg;
      if (grow < n) H[(size_t)grow * NF + cg * 16 + l15] = f2bf(acc[reg]);
    }
  }
}

// Stage W^T (f32 global -> bf16 LDS, [j][k] stride 72).
__device__ __forceinline__ void stage_wt(
    const float* __restrict__ W, unsigned short* __restrict__ Wt, int t) {
  #pragma unroll
  for (int i = 0; i < 16; ++i) {
    int idx = t + 256 * i;
    int k = idx >> 6, j = idx & 63;
    Wt[j * 72 + k] = f2bf(W[idx]);
  }
}

// Fused layer-1 MFMA GEMM + parallel atomic-free placement.
__global__ __launch_bounds__(256) void place_gemm1_kernel(
    const float* __restrict__ A, const float* __restrict__ so,
    const float* __restrict__ W, unsigned short* __restrict__ H, int n, int ggrid,
    const int* __restrict__ src, const int* __restrict__ dst,
    const unsigned char* __restrict__ rank, const int* __restrict__ base,
    unsigned short* __restrict__ sorted, int nE, int chunk) {
  __shared__ __align__(16) unsigned short Ab[64 * 72];
  __shared__ __align__(16) unsigned short Wt[64 * 72];
  const int t = threadIdx.x;
  if ((int)blockIdx.x >= ggrid) {
    int e = (blockIdx.x - ggrid) * 256 + t;
    if (e < nE) {
      int d = dst[e];
      int b = e / chunk;
      sorted[base[(size_t)b * n + d] + (int)rank[e]] = (unsigned short)src[e];
    }
    return;
  }
  stage_wt(W, Wt, t);
  const int row0 = blockIdx.x * 64;
  #pragma unroll
  for (int i = 0; i < 4; ++i) {
    int idx = t + 256 * i;
    int r = idx >> 4, c4 = idx & 15;
    int gr = row0 + r;
    float4 v = {0.f, 0.f, 0.f, 0.f};
    float s = 0.f;
    if (gr < n) {
      v = *(const float4*)&A[(size_t)gr * NF + c4 * 4];
      s = so[gr];
    }
    ushort4 o;
    o.x = f2bf(v.x * s); o.y = f2bf(v.y * s);
    o.z = f2bf(v.z * s); o.w = f2bf(v.w * s);
    *(ushort4*)&Ab[r * 72 + c4 * 4] = o;
  }
  __syncthreads();
  mfma_gemm_core(Ab, Wt, H, row0, n, t);
}

// Layer 2: h2 = bf16(t @ W2), bf16 input.
__global__ __launch_bounds__(256) void gemm2_kernel(
    const unsigned short* __restrict__ Tb, const float* __restrict__ W,
    unsigned short* __restrict__ H, int n) {
  __shared__ __align__(16) unsigned short Ab[64 * 72];
  __shared__ __align__(16) unsigned short Wt[64 * 72];
  const int t = threadIdx.x;
  stage_wt(W, Wt, t);
  const int row0 = blockIdx.x * 64;
  #pragma unroll
  for (int i = 0; i < 4; ++i) {
    int idx = t + 256 * i;
    int r = idx >> 4, c4 = idx & 15;
    int gr = row0 + r;
    ushort4 v = {0, 0, 0, 0};
    if (gr < n) v = *(const ushort4*)&Tb[(size_t)gr * NF + c4 * 4];
    *(ushort4*)&Ab[r * 72 + c4 * 4] = v;
  }
  __syncthreads();
  mfma_gemm_core(Ab, Wt, H, row0, n, t);
}

// ---------------------------------------------------------------------------
// Unsliced gather/accumulate (r12 version — sliced variants regressed: the
// agg is scattered-VMEM-transaction bound ~35 G lines/s, not footprint
// bound). One wave per node, bf16 rows = 128 B, 8 rows per VMEM instruction;
// butterfly leaves the full row sum in every lane.
__device__ __forceinline__ void gather_sum(
    const unsigned short* __restrict__ H, const unsigned short* __restrict__ srcs,
    int beg, int end, int g, int c, float* acc) {
  const float4* Hv = (const float4*)H;
  int e = beg;
  for (; e + 16 <= end; e += 16) {
    int ia = srcs[e + g];
    int ib = srcs[e + 8 + g];
    float4 va = Hv[(size_t)ia * 8 + c];
    float4 vb = Hv[(size_t)ib * 8 + c];
    const unsigned int* pa = (const unsigned int*)&va;
    const unsigned int* pb = (const unsigned int*)&vb;
    #pragma unroll
    for (int k = 0; k < 4; ++k) {
      acc[2 * k]     += __uint_as_float(pa[k] << 16) + __uint_as_float(pb[k] << 16);
      acc[2 * k + 1] += __uint_as_float(pa[k] & 0xffff0000u) + __uint_as_float(pb[k] & 0xffff0000u);
    }
  }
  if (e + 8 <= end) {
    int ia = srcs[e + g];
    float4 va = Hv[(size_t)ia * 8 + c];
    const unsigned int* pa = (const unsigned int*)&va;
    #pragma unroll
    for (int k = 0; k < 4; ++k) {
      acc[2 * k]     += __uint_as_float(pa[k] << 16);
      acc[2 * k + 1] += __uint_as_float(pa[k] & 0xffff0000u);
    }
    e += 8;
  }
  if (e < end) {
    int idx = (e + g < end) ? (e + g) : (end - 1);
    float m = (e + g < end) ? 1.f : 0.f;
    int ia = srcs[idx];
    float4 va = Hv[(size_t)ia * 8 + c];
    const unsigned int* pa = (const unsigned int*)&va;
    #pragma unroll
    for (int k = 0; k < 4; ++k) {
      acc[2 * k]     += m * __uint_as_float(pa[k] << 16);
      acc[2 * k + 1] += m * __uint_as_float(pa[k] & 0xffff0000u);
    }
  }
  #pragma unroll
  for (int d = 8; d <= 32; d <<= 1) {
    #pragma unroll
    for (int k = 0; k < 8; ++k) acc[k] += __shfl_xor(acc[k], d);
  }
}

// Layer-1 aggregation: t = bf16(relu(segsum(h1)*si + b1) * so).
__global__ __launch_bounds__(256) void agg1_kernel(
    const unsigned short* __restrict__ H1, const int* __restrict__ row_start,
    const unsigned short* __restrict__ srcs, const float* __restrict__ si,
    const float* __restrict__ so, const float* __restrict__ b1,
    unsigned short* __restrict__ T, int n) {
  int node = blockIdx.x * 4 + (threadIdx.x >> 6);
  if (node >= n) return;
  const int lane = threadIdx.x & 63;
  const int g = lane >> 3;
  const int c = lane & 7;
  float acc[8] = {0, 0, 0, 0, 0, 0, 0, 0};
  gather_sum(H1, srcs, row_start[node], row_start[node + 1], g, c, acc);
  if (g == 0) {
    const float sin = si[node];
    const float son = so[node];
    ushort4 o0, o1;
    float v;
    v = fmaxf(fmaf(acc[0], sin, b1[c * 8 + 0]), 0.f) * son; o0.x = f2bf(v);
    v = fmaxf(fmaf(acc[1], sin, b1[c * 8 + 1]), 0.f) * son; o0.y = f2bf(v);
    v = fmaxf(fmaf(acc[2], sin, b1[c * 8 + 2]), 0.f) * son; o0.z = f2bf(v);
    v = fmaxf(fmaf(acc[3], sin, b1[c * 8 + 3]), 0.f) * son; o0.w = f2bf(v);
    v = fmaxf(fmaf(acc[4], sin, b1[c * 8 + 4]), 0.f) * son; o1.x = f2bf(v);
    v = fmaxf(fmaf(acc[5], sin, b1[c * 8 + 5]), 0.f) * son; o1.y = f2bf(v);
    v = fmaxf(fmaf(acc[6], sin, b1[c * 8 + 6]), 0.f) * son; o1.z = f2bf(v);
    v = fmaxf(fmaf(acc[7], sin, b1[c * 8 + 7]), 0.f) * son; o1.w = f2bf(v);
    *(ushort4*)&T[(size_t)node * NF + c * 8]     = o0;
    *(ushort4*)&T[(size_t)node * NF + c * 8 + 4] = o1;
  }
}

// Layer-2 aggregation: out = segsum(h2)*si + b2 (f32).
__global__ __launch_bounds__(256) void agg2_kernel(
    const unsigned short* __restrict__ H2, const int* __restrict__ row_start,
    const unsigned short* __restrict__ srcs, const float* __restrict__ si,
    const float* __restrict__ b2, float* __restrict__ out, int n) {
  int node = blockIdx.x * 4 + (threadIdx.x >> 6);
  if (node >= n) return;
  const int lane = threadIdx.x & 63;
  const int g = lane >> 3;
  const int c = lane & 7;
  float acc[8] = {0, 0, 0, 0, 0, 0, 0, 0};
  gather_sum(H2, srcs, row_start[node], row_start[node + 1], g, c, acc);
  if (g == 0) {
    const float sin = si[node];
    const float4 b4a = *(const float4*)&b2[c * 8];
    const float4 b4b = *(const float4*)&b2[c * 8 + 4];
    float4 r0, r1;
    r0.x = fmaf(acc[0], sin, b4a.x);
    r0.y = fmaf(acc[1], sin, b4a.y);
    r0.z = fmaf(acc[2], sin, b4a.z);
    r0.w = fmaf(acc[3], sin, b4a.w);
    r1.x = fmaf(acc[4], sin, b4b.x);
    r1.y = fmaf(acc[5], sin, b4b.y);
    r1.z = fmaf(acc[6], sin, b4b.z);
    r1.w = fmaf(acc[7], sin, b4b.w);
    *(float4*)&out[(size_t)node * NF + c * 8]     = r0;
    *(float4*)&out[(size_t)node * NF + c * 8 + 4] = r1;
  }
}

// ---------------------------------------------------------------------------
extern "C" void kernel_launch(void* const* d_in, const int* in_sizes, int n_in,
                              void* d_out, int out_size, void* d_ws, size_t ws_size,
                              hipStream_t stream) {
  const float* x  = (const float*)d_in[0];
  const float* W1 = (const float*)d_in[1];
  const float* b1 = (const float*)d_in[2];
  const float* W2 = (const float*)d_in[3];
  const float* b2 = (const float*)d_in[4];
  const int* src  = (const int*)d_in[5];
  const int* dst  = (const int*)d_in[6];
  float* out = (float*)d_out;

  const int N = in_sizes[0] / NF;   // 50000 (< 65536 for ushort ids; %4==0)
  const int E = in_sizes[5];        // 800000
  const int NB = (N + 255) / 256;   // 196
  const int R  = (N + RANGE - 1) / RANGE;        // 4
  const int CH = (((E + BC - 1) / BC) + 3) & ~3; // 12500, 4-aligned
  (void)ws_size;

  // Workspace (~42 MB of 256 MiB; no aliasing — ws is large and re-poisoned
  // wholesale by the harness anyway).
  char* ws = (char*)d_ws;
  size_t p = 0;
  auto alloc = [&](size_t bytes) -> void* {
    void* r = ws + p;
    p = (p + bytes + 255) & ~(size_t)255;
    return r;
  };
  float* so         = (float*)alloc((size_t)N * 4);
  float* si         = (float*)alloc((size_t)N * 4);
  int*   row_start  = (int*)  alloc((size_t)(N + 1) * 4);
  int*   bsum       = (int*)  alloc((size_t)NB * 4);
  int*   lscan      = (int*)  alloc((size_t)N * 4);
  unsigned short* sorted_u16 = (unsigned short*)alloc((size_t)E * 2);
  unsigned char*  rank  = (unsigned char*)alloc((size_t)E);             // 0.8 MB
  unsigned short* h1    = (unsigned short*)alloc((size_t)N * NF * 2);   // 6.4 MB
  unsigned char*  G_in  = (unsigned char*)alloc((size_t)BC * N);        // 3.2 MB
  unsigned char*  G_out = (unsigned char*)alloc((size_t)BC * N);        // 3.2 MB
  unsigned short* tb    = (unsigned short*)alloc((size_t)N * NF * 2);   // 6.4 MB
  int*            base  = (int*)alloc((size_t)BC * N * 4);              // 12.8 MB
  unsigned short* h2 = h1;   // h1 dead once agg1 completes; gemm2 runs after

  // 1. packed-uchar histograms for both endpoints (+ rank capture)
  hist_kernel<<<2 * R * BC, 256, 0, stream>>>(src, dst, G_out, G_in, rank,
                                              N, E, R, CH);

  // 2. fused column-scan + degrees + si/so + block scan
  colscan_scan1_kernel<<<NB, 256, 0, stream>>>(G_in, G_out, so, si,
                                               lscan, bsum, N);

  // 3. row_start (slim scan finalize)
  scan3_kernel<<<NB, 256, 0, stream>>>(lscan, bsum, row_start, N, E);

  // 4. base[c][i] = row_start[i] + Gin[c][i] (fully parallel, coalesced)
  basefill_kernel<<<BC * NB, 256, 0, stream>>>(row_start, G_in, base, N, NB);

  const int ggrid = (N + 63) / 64;
  const int pgrid = (E + 255) / 256;
  const int agrid = (N + 3) / 4;

  // 5. fused: layer-1 MFMA GEMM (h1) + parallel atomic-free placement
  place_gemm1_kernel<<<ggrid + pgrid, 256, 0, stream>>>(
      x, so, W1, h1, N, ggrid, src, dst, rank, base, sorted_u16, E, CH);

  // 6. t = bf16(relu(segsum(h1)*si + b1) * so)
  agg1_kernel<<<agrid, 256, 0, stream>>>(h1, row_start, sorted_u16, si, so, b1, tb, N);

  // 7. h2 = bf16(t @ W2)   [MFMA]
  gemm2_kernel<<<ggrid, 256, 0, stream>>>(tb, W2, h2, N);

  // 8. out = segsum(h2)*si + b2
  agg2_kernel<<<agrid, 256, 0, stream>>>(h2, row_start, sorted_u16, si, b2, out, N);
}